// Round 1
// 8574.112 us; speedup vs baseline: 1.1838x; 1.1838x over previous
//
#include <hip/hip_runtime.h>
#include <hip/hip_bf16.h>

// Problem constants
#define BB 2
#define TT 2048
#define DD 512
#define HH 8
#define HS 64
#define VV 32000
#define FF 2048   // 4*D
#define MM (BB*TT) // 4096

typedef __attribute__((ext_vector_type(8))) __bf16 bf16x8;
typedef __attribute__((ext_vector_type(4))) float floatx4;

__device__ __forceinline__ ushort f2bf(float f) {
    union { float f; unsigned u; } x; x.f = f;
    unsigned u = x.u;
    return (ushort)((u + 0x7fffu + ((u >> 16) & 1u)) >> 16);
}

// ---------------------------------------------------------------------------
// Embedding: x[m][d] = tok_emb[idx[m]][d] + pos_emb[t][d]
// ---------------------------------------------------------------------------
__global__ __launch_bounds__(256) void embed_kernel(
    const int* __restrict__ idx, const float* __restrict__ tok,
    const float* __restrict__ pos, float* __restrict__ x)
{
    int i = blockIdx.x * 256 + threadIdx.x;   // over MM*DD
    int m = i >> 9;          // /512
    int d = i & 511;
    int t = m & (TT - 1);
    x[i] = tok[(size_t)idx[m] * DD + d] + pos[(size_t)t * DD + d];
}

// ---------------------------------------------------------------------------
// LayerNorm: one block (256 thr) per row of 512
// ---------------------------------------------------------------------------
__global__ __launch_bounds__(256) void ln_kernel(
    const float* __restrict__ x, const float* __restrict__ g,
    const float* __restrict__ b, float* __restrict__ out)
{
    int row = blockIdx.x;
    int tid = threadIdx.x;
    const float* xr = x + (size_t)row * DD;
    float v0 = xr[tid], v1 = xr[tid + 256];
    __shared__ float rs[256];
    rs[tid] = v0 + v1;
    __syncthreads();
    for (int off = 128; off > 0; off >>= 1) {
        if (tid < off) rs[tid] += rs[tid + off];
        __syncthreads();
    }
    float mean = rs[0] * (1.0f / DD);
    __syncthreads();
    float d0 = v0 - mean, d1 = v1 - mean;
    rs[tid] = d0 * d0 + d1 * d1;
    __syncthreads();
    for (int off = 128; off > 0; off >>= 1) {
        if (tid < off) rs[tid] += rs[tid + off];
        __syncthreads();
    }
    float rstd = rsqrtf(rs[0] * (1.0f / DD) + 1e-5f);
    float* o = out + (size_t)row * DD;
    o[tid]       = d0 * rstd * g[tid]       + b[tid];
    o[tid + 256] = d1 * rstd * g[tid + 256] + b[tid + 256];
}

// ---------------------------------------------------------------------------
// fp32 GEMM: C[M,N] = A[M,K] * W[K,N] + bias (+ residual) (+ relu)
// 64x64 tile, BK=16, 256 threads, 4x4 register tile per thread.
// ---------------------------------------------------------------------------
#define BM 64
#define BN 64
#define BK 16
#define LDSP 68   // padded leading dim

__global__ __launch_bounds__(256) void gemm_kernel(
    const float* __restrict__ A, const float* __restrict__ W,
    const float* __restrict__ bias, float* __restrict__ C,
    const float* __restrict__ res,
    int M, int N, int K, int relu)
{
    __shared__ float As[BK][LDSP];
    __shared__ float Bs[BK][LDSP];
    const int tid = threadIdx.x;
    const int row0 = blockIdx.y * BM;
    const int col0 = blockIdx.x * BN;
    const int tx = tid & 15, ty = tid >> 4;

    const int ar = tid >> 2, ac = (tid & 3) << 2;   // A tile: 64 rows x 16 cols
    const int wr = tid >> 4, wc = (tid & 15) << 2;  // W tile: 16 rows x 64 cols

    float acc[4][4] = {};

    for (int k0 = 0; k0 < K; k0 += BK) {
        float4 av = *(const float4*)(A + (size_t)(row0 + ar) * K + k0 + ac);
        As[ac + 0][ar] = av.x;
        As[ac + 1][ar] = av.y;
        As[ac + 2][ar] = av.z;
        As[ac + 3][ar] = av.w;
        float4 wv = *(const float4*)(W + (size_t)(k0 + wr) * N + col0 + wc);
        Bs[wr][wc + 0] = wv.x;
        Bs[wr][wc + 1] = wv.y;
        Bs[wr][wc + 2] = wv.z;
        Bs[wr][wc + 3] = wv.w;
        __syncthreads();
#pragma unroll
        for (int k = 0; k < BK; ++k) {
            float4 a = *(const float4*)&As[k][ty << 2];
            float4 bv = *(const float4*)&Bs[k][tx << 2];
            float aa[4] = {a.x, a.y, a.z, a.w};
            float bb[4] = {bv.x, bv.y, bv.z, bv.w};
#pragma unroll
            for (int i = 0; i < 4; ++i)
#pragma unroll
                for (int j = 0; j < 4; ++j)
                    acc[i][j] = fmaf(aa[i], bb[j], acc[i][j]);
        }
        __syncthreads();
    }

    // epilogue
#pragma unroll
    for (int i = 0; i < 4; ++i) {
        int r = row0 + (ty << 2) + i;
        size_t base = (size_t)r * N + col0 + (tx << 2);
#pragma unroll
        for (int j = 0; j < 4; ++j) {
            float v = acc[i][j];
            if (bias) v += bias[col0 + (tx << 2) + j];
            if (relu) v = fmaxf(v, 0.0f);
            if (res)  v += res[base + j];
            C[base + j] = v;
        }
    }
}

// ---------------------------------------------------------------------------
// Convert fp32 -> bf16 (flat, vectorized). n must be multiple of 1024.
// ---------------------------------------------------------------------------
__global__ __launch_bounds__(256) void cvt_bf16_kernel(
    const float* __restrict__ in, ushort* __restrict__ out)
{
    int i = (blockIdx.x * 256 + threadIdx.x) << 2;
    float4 v = *(const float4*)(in + i);
    ushort4 o = make_ushort4(f2bf(v.x), f2bf(v.y), f2bf(v.z), f2bf(v.w));
    *(ushort4*)(out + i) = o;
}

// ---------------------------------------------------------------------------
// Convert + transpose: W[K][N] fp32 -> WT[N][K] bf16. 32x32 tiles via LDS.
// ---------------------------------------------------------------------------
__global__ __launch_bounds__(256) void cvt_transpose_kernel(
    const float* __restrict__ W, ushort* __restrict__ WT, int K, int N)
{
    __shared__ float tile[32][33];
    const int n0 = blockIdx.x * 32, k0 = blockIdx.y * 32;
    const int tx = threadIdx.x & 31, ty = threadIdx.x >> 5;  // 32 x 8
#pragma unroll
    for (int i = 0; i < 32; i += 8)
        tile[ty + i][tx] = W[(size_t)(k0 + ty + i) * N + n0 + tx];
    __syncthreads();
#pragma unroll
    for (int i = 0; i < 32; i += 8)
        WT[(size_t)(n0 + ty + i) * K + k0 + tx] = f2bf(tile[tx][ty + i]);
}

// ---------------------------------------------------------------------------
// bf16 MFMA GEMM: C[M,N] = A[M,K](bf16) * BT[N,K](bf16)^T + bias, fp32 out.
// 128x128 tile, BK=32, 256 threads = 4 waves (2x2), each wave 64x64 via
// 4x4 fragments of v_mfma_f32_16x16x32_bf16. LDS padded to 40 bf16/row
// (80 B) -> fragment ds_read_b128 is ~2-way on banks (free, m136).
// ---------------------------------------------------------------------------
#define GBM 128
#define GBN 128
#define GBK 32
#define LDK 40

__global__ __launch_bounds__(256) void gemm_bf16_kernel(
    const ushort* __restrict__ A, const ushort* __restrict__ BT,
    const float* __restrict__ bias, float* __restrict__ C,
    int M, int N, int K)
{
    __shared__ __align__(16) ushort As[GBM][LDK];
    __shared__ __align__(16) ushort Bs[GBN][LDK];
    const int tid  = threadIdx.x;
    const int lane = tid & 63;
    const int wave = tid >> 6;
    const int wr = wave >> 1, wc = wave & 1;
    const int row0 = blockIdx.y * GBM;
    const int col0 = blockIdx.x * GBN;

    // staging: thread -> (srow, srow+64) x 8 bf16 at scol
    const int srow = tid >> 2;
    const int scol = (tid & 3) << 3;

    // fragment lane mapping (16x16x32): row/col = lane&15, k-chunk = lane>>4
    const int fr = lane & 15;
    const int kg = lane >> 4;

    floatx4 acc[4][4] = {};

    const ushort* Ap = A  + (size_t)(row0 + srow) * K + scol;
    const ushort* Bp = BT + (size_t)(col0 + srow) * K + scol;

    for (int k0 = 0; k0 < K; k0 += GBK) {
        uint4 av0 = *(const uint4*)(Ap + k0);
        uint4 av1 = *(const uint4*)(Ap + (size_t)64 * K + k0);
        uint4 bv0 = *(const uint4*)(Bp + k0);
        uint4 bv1 = *(const uint4*)(Bp + (size_t)64 * K + k0);
        *(uint4*)&As[srow][scol]      = av0;
        *(uint4*)&As[srow + 64][scol] = av1;
        *(uint4*)&Bs[srow][scol]      = bv0;
        *(uint4*)&Bs[srow + 64][scol] = bv1;
        __syncthreads();

        bf16x8 af[4], bf[4];
#pragma unroll
        for (int i = 0; i < 4; ++i)
            af[i] = *(const bf16x8*)&As[wr * 64 + i * 16 + fr][kg * 8];
#pragma unroll
        for (int j = 0; j < 4; ++j)
            bf[j] = *(const bf16x8*)&Bs[wc * 64 + j * 16 + fr][kg * 8];
#pragma unroll
        for (int i = 0; i < 4; ++i)
#pragma unroll
            for (int j = 0; j < 4; ++j)
                acc[i][j] = __builtin_amdgcn_mfma_f32_16x16x32_bf16(
                    af[i], bf[j], acc[i][j], 0, 0, 0);
        __syncthreads();
    }

    // epilogue: C/D layout (verified m89): col = lane&15, row = (lane>>4)*4+reg
    const int fq = lane >> 4;
#pragma unroll
    for (int i = 0; i < 4; ++i) {
        int r = row0 + wr * 64 + i * 16 + fq * 4;
#pragma unroll
        for (int j = 0; j < 4; ++j) {
            int c = col0 + wc * 64 + j * 16 + fr;
            float bv = bias ? bias[c] : 0.0f;
            float* cp = C + (size_t)r * N + c;
#pragma unroll
            for (int reg = 0; reg < 4; ++reg)
                cp[(size_t)reg * N] = acc[i][j][reg] + bv;
        }
    }
}

// ---------------------------------------------------------------------------
// Attention: one block (256 thr) per (b, h, t) query row. Two-pass softmax,
// scores staged in LDS (<= 2048 floats).
// ---------------------------------------------------------------------------
__global__ __launch_bounds__(256) void attn_kernel(
    const float* __restrict__ qf, const float* __restrict__ kf,
    const float* __restrict__ vf, float* __restrict__ att)
{
    const int t = blockIdx.x, h = blockIdx.y, b = blockIdx.z;
    const int tid = threadIdx.x;
    __shared__ float qs[HS];
    __shared__ float sc[TT];
    __shared__ float red[256];
    __shared__ float part[4][HS];
    const float scale = 0.044194173824159216f; // 512^-0.5

    const size_t baseq = ((size_t)(b * TT + t) * DD) + h * HS;
    if (tid < HS) qs[tid] = qf[baseq + tid];
    __syncthreads();

    // pass 1: scores for s <= t
    float lmax = -INFINITY;
    for (int s = tid; s <= t; s += 256) {
        const float* kp = kf + ((size_t)(b * TT + s) * DD) + h * HS;
        float dot = 0.0f;
#pragma unroll
        for (int d = 0; d < HS; d += 4) {
            float4 kv = *(const float4*)(kp + d);
            dot = fmaf(qs[d], kv.x, dot);
            dot = fmaf(qs[d + 1], kv.y, dot);
            dot = fmaf(qs[d + 2], kv.z, dot);
            dot = fmaf(qs[d + 3], kv.w, dot);
        }
        dot *= scale;
        sc[s] = dot;
        lmax = fmaxf(lmax, dot);
    }
    red[tid] = lmax;
    __syncthreads();
    for (int off = 128; off > 0; off >>= 1) {
        if (tid < off) red[tid] = fmaxf(red[tid], red[tid + off]);
        __syncthreads();
    }
    float m = red[0];
    __syncthreads();

    float lsum = 0.0f;
    for (int s = tid; s <= t; s += 256) {
        float e = __expf(sc[s] - m);
        sc[s] = e;
        lsum += e;
    }
    red[tid] = lsum;
    __syncthreads();
    for (int off = 128; off > 0; off >>= 1) {
        if (tid < off) red[tid] += red[tid + off];
        __syncthreads();
    }
    float linv = 1.0f / red[0];
    __syncthreads();

    // pass 2: out[d] = sum_s w[s] * v[s][d]
    const int g = tid >> 6, lane = tid & 63;
    float acc = 0.0f;
    for (int s = g; s <= t; s += 4) {
        acc = fmaf(sc[s], vf[((size_t)(b * TT + s) * DD) + h * HS + lane], acc);
    }
    part[g][lane] = acc;
    __syncthreads();
    if (g == 0) {
        float tot = (part[0][lane] + part[1][lane] + part[2][lane] + part[3][lane]) * linv;
        att[baseq + lane] = tot;
    }
}

// ---------------------------------------------------------------------------
// Launch
// ---------------------------------------------------------------------------
extern "C" void kernel_launch(void* const* d_in, const int* in_sizes, int n_in,
                              void* d_out, int out_size, void* d_ws, size_t ws_size,
                              hipStream_t stream) {
    const int*   idx    = (const int*)  d_in[0];
    const float* tok    = (const float*)d_in[1];
    const float* pos    = (const float*)d_in[2];
    const float* ln1_g  = (const float*)d_in[3];
    const float* ln1_b  = (const float*)d_in[4];
    const float* Wq     = (const float*)d_in[5];
    const float* Wk     = (const float*)d_in[6];
    const float* Wv     = (const float*)d_in[7];
    const float* Wo     = (const float*)d_in[8];
    const float* bo     = (const float*)d_in[9];
    const float* ln2_g  = (const float*)d_in[10];
    const float* ln2_b  = (const float*)d_in[11];
    const float* W1     = (const float*)d_in[12];
    const float* b1     = (const float*)d_in[13];
    const float* W2     = (const float*)d_in[14];
    const float* b2     = (const float*)d_in[15];
    const float* lm_W   = (const float*)d_in[16];
    const float* lm_b   = (const float*)d_in[17];
    float* out = (float*)d_out;

    // workspace layout (floats):
    //   x (2M) | h (2M) | big (8M: q/k/v then ffn-mid) | xb (1M: 2M bf16)
    //   | WT (8M: 16M bf16 = lm_W^T)
    float* ws  = (float*)d_ws;
    float* xf  = ws;
    float* hf  = ws + (1u << 21);
    float* big = ws + (2u << 21);
    float* qf  = big;
    float* kf  = big + (1u << 21);
    float* vf  = big + (2u << 21);
    float* mid = big;
    ushort* xb = (ushort*)(ws + (12u << 20));
    ushort* WT = (ushort*)(ws + (13u << 20));

    dim3 blk(256);

    // lm_W fp32 [D][V] -> bf16 [V][D] (independent of everything else)
    cvt_transpose_kernel<<<dim3(VV / 32, DD / 32), blk, 0, stream>>>(lm_W, WT, DD, VV);

    embed_kernel<<<dim3((MM * DD) / 256), blk, 0, stream>>>(idx, tok, pos, xf);

    for (int l = 0; l < 4; ++l) {
        ln_kernel<<<dim3(MM), blk, 0, stream>>>(xf, ln1_g + l * DD, ln1_b + l * DD, hf);
        gemm_kernel<<<dim3(DD / BN, MM / BM), blk, 0, stream>>>(
            hf, Wq + (size_t)l * DD * DD, nullptr, qf, nullptr, MM, DD, DD, 0);
        gemm_kernel<<<dim3(DD / BN, MM / BM), blk, 0, stream>>>(
            hf, Wk + (size_t)l * DD * DD, nullptr, kf, nullptr, MM, DD, DD, 0);
        gemm_kernel<<<dim3(DD / BN, MM / BM), blk, 0, stream>>>(
            hf, Wv + (size_t)l * DD * DD, nullptr, vf, nullptr, MM, DD, DD, 0);
        attn_kernel<<<dim3(TT, HH, BB), blk, 0, stream>>>(qf, kf, vf, hf);
        gemm_kernel<<<dim3(DD / BN, MM / BM), blk, 0, stream>>>(
            hf, Wo + (size_t)l * DD * DD, bo + l * DD, xf, xf, MM, DD, DD, 0);
        ln_kernel<<<dim3(MM), blk, 0, stream>>>(xf, ln2_g + l * DD, ln2_b + l * DD, hf);
        gemm_kernel<<<dim3(FF / BN, MM / BM), blk, 0, stream>>>(
            hf, W1 + (size_t)l * DD * FF, b1 + l * FF, mid, nullptr, MM, FF, DD, 1);
        gemm_kernel<<<dim3(DD / BN, MM / BM), blk, 0, stream>>>(
            mid, W2 + (size_t)l * FF * DD, b2 + l * DD, xf, xf, MM, DD, FF, 0);
    }

    // LM head in bf16 MFMA: x -> bf16, then C = xb @ WT^T + lm_b
    cvt_bf16_kernel<<<dim3((MM * DD) / 1024), blk, 0, stream>>>(xf, xb);
    gemm_bf16_kernel<<<dim3(VV / GBN, MM / GBM), blk, 0, stream>>>(
        xb, WT, lm_b, out, MM, VV, DD);
}

// Round 2
// 3815.704 us; speedup vs baseline: 2.6600x; 2.2471x over previous
//
#include <hip/hip_runtime.h>
#include <hip/hip_bf16.h>

// Problem constants
#define BB 2
#define TT 2048
#define DD 512
#define HH 8
#define HS 64
#define VV 32000
#define FF 2048   // 4*D
#define MM (BB*TT) // 4096

typedef __attribute__((ext_vector_type(8))) __bf16 bf16x8;
typedef __attribute__((ext_vector_type(4))) float floatx4;

__device__ __forceinline__ ushort f2bf(float f) {
    union { float f; unsigned u; } x; x.f = f;
    unsigned u = x.u;
    return (ushort)((u + 0x7fffu + ((u >> 16) & 1u)) >> 16);
}

// ---------------------------------------------------------------------------
// Embedding: x[m][d] = tok_emb[idx[m]][d] + pos_emb[t][d]
// ---------------------------------------------------------------------------
__global__ __launch_bounds__(256) void embed_kernel(
    const int* __restrict__ idx, const float* __restrict__ tok,
    const float* __restrict__ pos, float* __restrict__ x)
{
    int i = blockIdx.x * 256 + threadIdx.x;   // over MM*DD
    int m = i >> 9;          // /512
    int d = i & 511;
    int t = m & (TT - 1);
    x[i] = tok[(size_t)idx[m] * DD + d] + pos[(size_t)t * DD + d];
}

// ---------------------------------------------------------------------------
// LayerNorm: one block (256 thr) per row of 512
// ---------------------------------------------------------------------------
__global__ __launch_bounds__(256) void ln_kernel(
    const float* __restrict__ x, const float* __restrict__ g,
    const float* __restrict__ b, float* __restrict__ out)
{
    int row = blockIdx.x;
    int tid = threadIdx.x;
    const float* xr = x + (size_t)row * DD;
    float v0 = xr[tid], v1 = xr[tid + 256];
    __shared__ float rs[256];
    rs[tid] = v0 + v1;
    __syncthreads();
    for (int off = 128; off > 0; off >>= 1) {
        if (tid < off) rs[tid] += rs[tid + off];
        __syncthreads();
    }
    float mean = rs[0] * (1.0f / DD);
    __syncthreads();
    float d0 = v0 - mean, d1 = v1 - mean;
    rs[tid] = d0 * d0 + d1 * d1;
    __syncthreads();
    for (int off = 128; off > 0; off >>= 1) {
        if (tid < off) rs[tid] += rs[tid + off];
        __syncthreads();
    }
    float rstd = rsqrtf(rs[0] * (1.0f / DD) + 1e-5f);
    float* o = out + (size_t)row * DD;
    o[tid]       = d0 * rstd * g[tid]       + b[tid];
    o[tid + 256] = d1 * rstd * g[tid + 256] + b[tid + 256];
}

// ---------------------------------------------------------------------------
// fp32 GEMM: C[M,N] = A[M,K] * W[K,N] + bias (+ residual) (+ relu)
// 64x64 tile, BK=16, 256 threads, 4x4 register tile per thread.
// ---------------------------------------------------------------------------
#define BM 64
#define BN 64
#define BK 16
#define LDSP 68   // padded leading dim

__global__ __launch_bounds__(256) void gemm_kernel(
    const float* __restrict__ A, const float* __restrict__ W,
    const float* __restrict__ bias, float* __restrict__ C,
    const float* __restrict__ res,
    int M, int N, int K, int relu)
{
    __shared__ float As[BK][LDSP];
    __shared__ float Bs[BK][LDSP];
    const int tid = threadIdx.x;
    const int row0 = blockIdx.y * BM;
    const int col0 = blockIdx.x * BN;
    const int tx = tid & 15, ty = tid >> 4;

    const int ar = tid >> 2, ac = (tid & 3) << 2;   // A tile: 64 rows x 16 cols
    const int wr = tid >> 4, wc = (tid & 15) << 2;  // W tile: 16 rows x 64 cols

    float acc[4][4] = {};

    for (int k0 = 0; k0 < K; k0 += BK) {
        float4 av = *(const float4*)(A + (size_t)(row0 + ar) * K + k0 + ac);
        As[ac + 0][ar] = av.x;
        As[ac + 1][ar] = av.y;
        As[ac + 2][ar] = av.z;
        As[ac + 3][ar] = av.w;
        float4 wv = *(const float4*)(W + (size_t)(k0 + wr) * N + col0 + wc);
        Bs[wr][wc + 0] = wv.x;
        Bs[wr][wc + 1] = wv.y;
        Bs[wr][wc + 2] = wv.z;
        Bs[wr][wc + 3] = wv.w;
        __syncthreads();
#pragma unroll
        for (int k = 0; k < BK; ++k) {
            float4 a = *(const float4*)&As[k][ty << 2];
            float4 bv = *(const float4*)&Bs[k][tx << 2];
            float aa[4] = {a.x, a.y, a.z, a.w};
            float bb[4] = {bv.x, bv.y, bv.z, bv.w};
#pragma unroll
            for (int i = 0; i < 4; ++i)
#pragma unroll
                for (int j = 0; j < 4; ++j)
                    acc[i][j] = fmaf(aa[i], bb[j], acc[i][j]);
        }
        __syncthreads();
    }

    // epilogue
#pragma unroll
    for (int i = 0; i < 4; ++i) {
        int r = row0 + (ty << 2) + i;
        size_t base = (size_t)r * N + col0 + (tx << 2);
#pragma unroll
        for (int j = 0; j < 4; ++j) {
            float v = acc[i][j];
            if (bias) v += bias[col0 + (tx << 2) + j];
            if (relu) v = fmaxf(v, 0.0f);
            if (res)  v += res[base + j];
            C[base + j] = v;
        }
    }
}

// ---------------------------------------------------------------------------
// Convert fp32 -> bf16 (flat, vectorized). n must be multiple of 1024.
// ---------------------------------------------------------------------------
__global__ __launch_bounds__(256) void cvt_bf16_kernel(
    const float* __restrict__ in, ushort* __restrict__ out)
{
    int i = (blockIdx.x * 256 + threadIdx.x) << 2;
    float4 v = *(const float4*)(in + i);
    ushort4 o = make_ushort4(f2bf(v.x), f2bf(v.y), f2bf(v.z), f2bf(v.w));
    *(ushort4*)(out + i) = o;
}

// ---------------------------------------------------------------------------
// Convert + transpose: W[K][N] fp32 -> WT[N][K] bf16. 32x32 tiles via LDS.
// ---------------------------------------------------------------------------
__global__ __launch_bounds__(256) void cvt_transpose_kernel(
    const float* __restrict__ W, ushort* __restrict__ WT, int K, int N)
{
    __shared__ float tile[32][33];
    const int n0 = blockIdx.x * 32, k0 = blockIdx.y * 32;
    const int tx = threadIdx.x & 31, ty = threadIdx.x >> 5;  // 32 x 8
#pragma unroll
    for (int i = 0; i < 32; i += 8)
        tile[ty + i][tx] = W[(size_t)(k0 + ty + i) * N + n0 + tx];
    __syncthreads();
#pragma unroll
    for (int i = 0; i < 32; i += 8)
        WT[(size_t)(n0 + ty + i) * K + k0 + tx] = f2bf(tile[tx][ty + i]);
}

// ---------------------------------------------------------------------------
// bf16 MFMA GEMM: C[M,N] = A[M,K](bf16) * BT[N,K](bf16)^T + bias, fp32 out.
// 128x128 tile, BK=32, 256 threads = 4 waves (2x2).
// ---------------------------------------------------------------------------
#define GBM 128
#define GBN 128
#define GBK 32
#define LDK 40

__global__ __launch_bounds__(256) void gemm_bf16_kernel(
    const ushort* __restrict__ A, const ushort* __restrict__ BT,
    const float* __restrict__ bias, float* __restrict__ C,
    int M, int N, int K)
{
    __shared__ __align__(16) ushort As[GBM][LDK];
    __shared__ __align__(16) ushort Bs[GBN][LDK];
    const int tid  = threadIdx.x;
    const int lane = tid & 63;
    const int wave = tid >> 6;
    const int wr = wave >> 1, wc = wave & 1;
    const int row0 = blockIdx.y * GBM;
    const int col0 = blockIdx.x * GBN;

    const int srow = tid >> 2;
    const int scol = (tid & 3) << 3;

    const int fr = lane & 15;
    const int kg = lane >> 4;

    floatx4 acc[4][4] = {};

    const ushort* Ap = A  + (size_t)(row0 + srow) * K + scol;
    const ushort* Bp = BT + (size_t)(col0 + srow) * K + scol;

    for (int k0 = 0; k0 < K; k0 += GBK) {
        uint4 av0 = *(const uint4*)(Ap + k0);
        uint4 av1 = *(const uint4*)(Ap + (size_t)64 * K + k0);
        uint4 bv0 = *(const uint4*)(Bp + k0);
        uint4 bv1 = *(const uint4*)(Bp + (size_t)64 * K + k0);
        *(uint4*)&As[srow][scol]      = av0;
        *(uint4*)&As[srow + 64][scol] = av1;
        *(uint4*)&Bs[srow][scol]      = bv0;
        *(uint4*)&Bs[srow + 64][scol] = bv1;
        __syncthreads();

        bf16x8 af[4], bf[4];
#pragma unroll
        for (int i = 0; i < 4; ++i)
            af[i] = *(const bf16x8*)&As[wr * 64 + i * 16 + fr][kg * 8];
#pragma unroll
        for (int j = 0; j < 4; ++j)
            bf[j] = *(const bf16x8*)&Bs[wc * 64 + j * 16 + fr][kg * 8];
#pragma unroll
        for (int i = 0; i < 4; ++i)
#pragma unroll
            for (int j = 0; j < 4; ++j)
                acc[i][j] = __builtin_amdgcn_mfma_f32_16x16x32_bf16(
                    af[i], bf[j], acc[i][j], 0, 0, 0);
        __syncthreads();
    }

    const int fq = lane >> 4;
#pragma unroll
    for (int i = 0; i < 4; ++i) {
        int r = row0 + wr * 64 + i * 16 + fq * 4;
#pragma unroll
        for (int j = 0; j < 4; ++j) {
            int c = col0 + wc * 64 + j * 16 + fr;
            float bv = bias ? bias[c] : 0.0f;
            float* cp = C + (size_t)r * N + c;
#pragma unroll
            for (int reg = 0; reg < 4; ++reg)
                cp[(size_t)reg * N] = acc[i][j][reg] + bv;
        }
    }
}

// ---------------------------------------------------------------------------
// Flash-style fp32 attention.
// One block (256 thr = 16x16) per 64-query tile per (b,h). Grid (T/64, H, B).
// K-tile staged transposed [d][s] in LDS, V natural [s][d]. Scores via
// 4x4 register tile (same structure as gemm_kernel). Online softmax with
// __shfl_xor row-reductions (row group = 16 consecutive lanes). P is written
// back into the K buffer (aliased) for the PV GEMM. All fp32.
// ---------------------------------------------------------------------------
#define QB 64
#define SB 64
#define ALD 68   // padded leading dim (floats): float4-aligned rows

__global__ __launch_bounds__(256) void attn_kernel(
    const float* __restrict__ qf, const float* __restrict__ kf,
    const float* __restrict__ vf, float* __restrict__ att)
{
    __shared__ float Qs[SB][ALD];   // [d][q]  (transposed Q tile, persists)
    __shared__ float KPs[SB][ALD];  // K: [d][s]; reused as P: [s][q]
    __shared__ float Vs[SB][ALD];   // [s][d]
    const int tid = threadIdx.x;
    const int tx = tid & 15, ty = tid >> 4;
    const int q0 = blockIdx.x * QB;
    const int h = blockIdx.y, b = blockIdx.z;
    const float scale = 0.044194173824159216f; // 512^-0.5
    const size_t hoff = (size_t)h * HS;

    // stage Q transposed: Qs[d][q]
#pragma unroll
    for (int rep = 0; rep < 4; ++rep) {
        int r = (tid >> 4) + rep * 16;   // q row 0..63
        int c4 = tid & 15;               // d chunk
        float4 v = *(const float4*)(qf + ((size_t)(b * TT + q0 + r) * DD) + hoff + c4 * 4);
        Qs[c4 * 4 + 0][r] = v.x;
        Qs[c4 * 4 + 1][r] = v.y;
        Qs[c4 * 4 + 2][r] = v.z;
        Qs[c4 * 4 + 3][r] = v.w;
    }

    float m_i[4], l_i[4];
    float acc[4][4] = {};
#pragma unroll
    for (int i = 0; i < 4; ++i) { m_i[i] = -INFINITY; l_i[i] = 0.0f; }

    for (int s0 = 0; s0 <= q0; s0 += SB) {
        __syncthreads();   // previous tile's KPs/Vs reads done (also Q vis on iter 0)
        // stage K transposed [d][s] and V natural [s][d]
#pragma unroll
        for (int rep = 0; rep < 4; ++rep) {
            int r = (tid >> 4) + rep * 16;
            int c4 = tid & 15;
            size_t rb = (size_t)(b * TT + s0 + r) * DD + hoff + c4 * 4;
            float4 kv = *(const float4*)(kf + rb);
            KPs[c4 * 4 + 0][r] = kv.x;
            KPs[c4 * 4 + 1][r] = kv.y;
            KPs[c4 * 4 + 2][r] = kv.z;
            KPs[c4 * 4 + 3][r] = kv.w;
            float4 vv = *(const float4*)(vf + rb);
            *(float4*)&Vs[r][c4 * 4] = vv;
        }
        __syncthreads();

        // scores: sc[i][j] = sum_d Q[q0+ty*4+i][d] * K[s0+tx*4+j][d]
        float sc[4][4] = {};
#pragma unroll 8
        for (int d = 0; d < SB; ++d) {
            float4 a = *(const float4*)&Qs[d][ty << 2];
            float4 kq = *(const float4*)&KPs[d][tx << 2];
            float aa[4] = {a.x, a.y, a.z, a.w};
            float bb[4] = {kq.x, kq.y, kq.z, kq.w};
#pragma unroll
            for (int i = 0; i < 4; ++i)
#pragma unroll
                for (int j = 0; j < 4; ++j)
                    sc[i][j] = fmaf(aa[i], bb[j], sc[i][j]);
        }

        // scale + causal mask (only the diagonal tile has masked entries)
        if (s0 == q0) {
#pragma unroll
            for (int i = 0; i < 4; ++i)
#pragma unroll
                for (int j = 0; j < 4; ++j)
                    sc[i][j] = ((tx << 2) + j > (ty << 2) + i) ? -INFINITY
                                                               : sc[i][j] * scale;
        } else {
#pragma unroll
            for (int i = 0; i < 4; ++i)
#pragma unroll
                for (int j = 0; j < 4; ++j)
                    sc[i][j] *= scale;
        }

        // online softmax; row group = 16 lanes sharing ty
#pragma unroll
        for (int i = 0; i < 4; ++i) {
            float rm = fmaxf(fmaxf(sc[i][0], sc[i][1]), fmaxf(sc[i][2], sc[i][3]));
#pragma unroll
            for (int off = 8; off > 0; off >>= 1)
                rm = fmaxf(rm, __shfl_xor(rm, off));
            float mn = fmaxf(m_i[i], rm);
            float corr = __expf(m_i[i] - mn);
            float rs = 0.0f;
#pragma unroll
            for (int j = 0; j < 4; ++j) {
                float p = __expf(sc[i][j] - mn);
                sc[i][j] = p;
                rs += p;
            }
#pragma unroll
            for (int off = 8; off > 0; off >>= 1)
                rs += __shfl_xor(rs, off);
            l_i[i] = l_i[i] * corr + rs;
            m_i[i] = mn;
#pragma unroll
            for (int j = 0; j < 4; ++j) acc[i][j] *= corr;
        }

        __syncthreads();   // all K reads done; safe to overwrite with P
        // write P transposed: KPs[s][q]
#pragma unroll
        for (int j = 0; j < 4; ++j)
#pragma unroll
            for (int i = 0; i < 4; ++i)
                KPs[(tx << 2) + j][(ty << 2) + i] = sc[i][j];
        __syncthreads();

        // PV: acc[i][j] += sum_s P[q][s] * V[s][d]
#pragma unroll 8
        for (int s = 0; s < SB; ++s) {
            float4 p4 = *(const float4*)&KPs[s][ty << 2];
            float4 v4 = *(const float4*)&Vs[s][tx << 2];
            float pp[4] = {p4.x, p4.y, p4.z, p4.w};
            float vv[4] = {v4.x, v4.y, v4.z, v4.w};
#pragma unroll
            for (int i = 0; i < 4; ++i)
#pragma unroll
                for (int j = 0; j < 4; ++j)
                    acc[i][j] = fmaf(pp[i], vv[j], acc[i][j]);
        }
    }

    // epilogue: out = acc / l
#pragma unroll
    for (int i = 0; i < 4; ++i) {
        float inv = 1.0f / l_i[i];
        int q = q0 + (ty << 2) + i;
        float4 o;
        o.x = acc[i][0] * inv;
        o.y = acc[i][1] * inv;
        o.z = acc[i][2] * inv;
        o.w = acc[i][3] * inv;
        *(float4*)(att + ((size_t)(b * TT + q) * DD) + hoff + (tx << 2)) = o;
    }
}

// ---------------------------------------------------------------------------
// Launch
// ---------------------------------------------------------------------------
extern "C" void kernel_launch(void* const* d_in, const int* in_sizes, int n_in,
                              void* d_out, int out_size, void* d_ws, size_t ws_size,
                              hipStream_t stream) {
    const int*   idx    = (const int*)  d_in[0];
    const float* tok    = (const float*)d_in[1];
    const float* pos    = (const float*)d_in[2];
    const float* ln1_g  = (const float*)d_in[3];
    const float* ln1_b  = (const float*)d_in[4];
    const float* Wq     = (const float*)d_in[5];
    const float* Wk     = (const float*)d_in[6];
    const float* Wv     = (const float*)d_in[7];
    const float* Wo     = (const float*)d_in[8];
    const float* bo     = (const float*)d_in[9];
    const float* ln2_g  = (const float*)d_in[10];
    const float* ln2_b  = (const float*)d_in[11];
    const float* W1     = (const float*)d_in[12];
    const float* b1     = (const float*)d_in[13];
    const float* W2     = (const float*)d_in[14];
    const float* b2     = (const float*)d_in[15];
    const float* lm_W   = (const float*)d_in[16];
    const float* lm_b   = (const float*)d_in[17];
    float* out = (float*)d_out;

    // workspace layout (floats):
    //   x (2M) | h (2M) | big (8M: q/k/v then ffn-mid) | xb (1M: 2M bf16)
    //   | WT (8M: 16M bf16 = lm_W^T)
    float* ws  = (float*)d_ws;
    float* xf  = ws;
    float* hf  = ws + (1u << 21);
    float* big = ws + (2u << 21);
    float* qf  = big;
    float* kf  = big + (1u << 21);
    float* vf  = big + (2u << 21);
    float* mid = big;
    ushort* xb = (ushort*)(ws + (12u << 20));
    ushort* WT = (ushort*)(ws + (13u << 20));

    dim3 blk(256);

    // lm_W fp32 [D][V] -> bf16 [V][D] (independent of everything else)
    cvt_transpose_kernel<<<dim3(VV / 32, DD / 32), blk, 0, stream>>>(lm_W, WT, DD, VV);

    embed_kernel<<<dim3((MM * DD) / 256), blk, 0, stream>>>(idx, tok, pos, xf);

    for (int l = 0; l < 4; ++l) {
        ln_kernel<<<dim3(MM), blk, 0, stream>>>(xf, ln1_g + l * DD, ln1_b + l * DD, hf);
        gemm_kernel<<<dim3(DD / BN, MM / BM), blk, 0, stream>>>(
            hf, Wq + (size_t)l * DD * DD, nullptr, qf, nullptr, MM, DD, DD, 0);
        gemm_kernel<<<dim3(DD / BN, MM / BM), blk, 0, stream>>>(
            hf, Wk + (size_t)l * DD * DD, nullptr, kf, nullptr, MM, DD, DD, 0);
        gemm_kernel<<<dim3(DD / BN, MM / BM), blk, 0, stream>>>(
            hf, Wv + (size_t)l * DD * DD, nullptr, vf, nullptr, MM, DD, DD, 0);
        attn_kernel<<<dim3(TT / QB, HH, BB), blk, 0, stream>>>(qf, kf, vf, hf);
        gemm_kernel<<<dim3(DD / BN, MM / BM), blk, 0, stream>>>(
            hf, Wo + (size_t)l * DD * DD, bo + l * DD, xf, xf, MM, DD, DD, 0);
        ln_kernel<<<dim3(MM), blk, 0, stream>>>(xf, ln2_g + l * DD, ln2_b + l * DD, hf);
        gemm_kernel<<<dim3(FF / BN, MM / BM), blk, 0, stream>>>(
            hf, W1 + (size_t)l * DD * FF, b1 + l * FF, mid, nullptr, MM, FF, DD, 1);
        gemm_kernel<<<dim3(DD / BN, MM / BM), blk, 0, stream>>>(
            mid, W2 + (size_t)l * FF * DD, b2 + l * DD, xf, xf, MM, DD, FF, 0);
    }

    // LM head in bf16 MFMA: x -> bf16, then C = xb @ WT^T + lm_b
    cvt_bf16_kernel<<<dim3((MM * DD) / 1024), blk, 0, stream>>>(xf, xb);
    gemm_bf16_kernel<<<dim3(VV / GBN, MM / GBM), blk, 0, stream>>>(
        xb, WT, lm_b, out, MM, VV, DD);
}